// Round 1
// baseline (3058.640 us; speedup 1.0000x reference)
//
#include <hip/hip_runtime.h>
#include <math.h>

#define S   612
#define TT  8192
#define NB  32
#define BS  640
#define NWAVE 10

// workspace layout (bytes)
#define WIN_OFF   0        // 612*4 floats  = 9792 B
#define IV_OFF    12288    // 4 floats
#define EMIS_OFF  16384    // 100*612 floats = 244800 B
#define OBS_OFF   262144   // 32*8192 ints  = 1 MB

__global__ __launch_bounds__(256) void prep_tables(
    const float* __restrict__ tk, const float* __restrict__ ik,
    float* __restrict__ wIn, float* __restrict__ Ivec)
{
    int i = blockIdx.x * 256 + threadIdx.x;
    if (i < S) {
        float l0 = tk[3*i], l1 = tk[3*i+1], l2 = tk[3*i+2], l3 = 1.0f;
        float m = fmaxf(fmaxf(l0, l1), fmaxf(l2, l3));
        float e0 = expf(l0-m), e1 = expf(l1-m), e2 = expf(l2-m), e3 = expf(l3-m);
        float inv = 1.0f / (e0+e1+e2+e3);
        // scatter into incoming layout: wIn[(i+j)%S][j] = p_j
        wIn[i*4 + 0]             = e0*inv;
        wIn[((i+1)%S)*4 + 1]     = e1*inv;
        wIn[((i+2)%S)*4 + 2]     = e2*inv;
        wIn[((i+3)%S)*4 + 3]     = e3*inv;
    } else if (i == S) {
        float l0 = ik[0], l1 = ik[1], l2 = ik[2], l3 = ik[3];
        float m = fmaxf(fmaxf(l0,l1), fmaxf(l2,l3));
        float e0 = expf(l0-m), e1 = expf(l1-m), e2 = expf(l2-m), e3 = expf(l3-m);
        float inv = 1.0f / (e0+e1+e2+e3);
        Ivec[0]=e0*inv; Ivec[1]=e1*inv; Ivec[2]=e2*inv; Ivec[3]=e3*inv;
    }
}

__global__ __launch_bounds__(256) void prep_emis(
    const float* __restrict__ ek, float* __restrict__ emisT)
{
    int tid = blockIdx.x * 256 + threadIdx.x;       // tid = o*S + s
    if (tid >= 100*S) return;
    int s = tid % S;
    int o = tid / S;
    float val = 0.0f;
    if (s < S-1) {
        int c = o >> 2, l = o & 3;
        if (c == 0) {
            val = 0.25f;
        } else {
            const float* g = ek + s*96 + (c-1)*4;
            float a0=g[0], a1=g[1], a2=g[2], a3=g[3];
            float m = fmaxf(fmaxf(a0,a1), fmaxf(a2,a3));
            float x0=expf(a0-m), x1=expf(a1-m), x2=expf(a2-m), x3=expf(a3-m);
            float inv = 1.0f/(x0+x1+x2+x3);
            float sel = (l==0)?x0:(l==1)?x1:(l==2)?x2:x3;
            val = sel * inv;
        }
    }
    emisT[tid] = val;   // emisT[o][s], s-fastest -> coalesced
}

// one wave per one-hot row: o = round(dot(row, iota))
__global__ __launch_bounds__(256) void extract_obs(
    const float* __restrict__ x, int* __restrict__ obs)
{
    int row  = blockIdx.x * 4 + (threadIdx.x >> 6);
    int lane = threadIdx.x & 63;
    if (row >= NB*TT) return;
    const float* r = x + (size_t)row * 101;
    float acc = r[lane] * (float)lane;
    if (lane < 37) acc += r[64 + lane] * (float)(64 + lane);
    #pragma unroll
    for (int m = 32; m >= 1; m >>= 1) acc += __shfl_xor(acc, m, 64);
    if (lane == 0) obs[row] = (int)(acc + 0.5f);
}

__global__ __launch_bounds__(BS) void forward(
    const float* __restrict__ emisT, const float* __restrict__ wIn,
    const float* __restrict__ Ivec, const int* __restrict__ obs,
    float* __restrict__ out)
{
    __shared__ float buf0[S + 4];
    __shared__ float buf1[S + 4];
    __shared__ float red[NWAVE];
    __shared__ int   obs_s[TT];

    const int tid = threadIdx.x;
    const int b   = blockIdx.x;
    const int s   = tid;
    const bool act = (s < S);

    for (int i = tid; i < TT; i += BS) obs_s[i] = obs[b*TT + i];

    float w0=0, w1=0, w2=0, w3=0;
    if (act) {
        float4 wv = *reinterpret_cast<const float4*>(wIn + 4*s);
        w0 = wv.x; w1 = wv.y; w2 = wv.z; w3 = wv.w;
    }
    __syncthreads();

    // t = 0
    float a = 0.0f;
    if (act) {
        int o0 = obs_s[0];
        float Iv = (s < 4) ? Ivec[s] : 0.0f;
        a = emisT[o0*S + s] * Iv;
    }
    float ll = 0.0f;
    {
        float v = act ? a : 0.0f;
        #pragma unroll
        for (int m = 32; m >= 1; m >>= 1) v += __shfl_xor(v, m, 64);
        if ((tid & 63) == 0) red[tid >> 6] = v;
        __syncthreads();
        float Z = 0.0f;
        #pragma unroll
        for (int wv = 0; wv < NWAVE; ++wv) Z += red[wv];
        ll += logf(Z);
        a *= (1.0f / Z);
    }

    // prefetch emission for t = 1
    float e = 0.0f;
    if (act) e = emisT[obs_s[1]*S + s];

    int p = 0;
    for (int t = 1; t < TT; ++t) {
        float* al = p ? buf1 : buf0;
        if (act) {
            al[3 + s] = a;
            if (s >= S-3) al[s - (S-3)] = a;   // wrap pad: al[0..2] = alpha[S-3..S-1]
        }
        __syncthreads();
        float enext = 0.0f;
        if (act && t + 1 < TT) enext = emisT[obs_s[t+1]*S + s];
        if (act) {
            float sum = al[3+s]*w0 + al[2+s]*w1 + al[1+s]*w2 + al[s]*w3;
            a = e * sum;
        }
        e = enext;
        p ^= 1;
        if ((t & 7) == 0) {     // renorm every 8 steps
            float v = act ? a : 0.0f;
            #pragma unroll
            for (int m = 32; m >= 1; m >>= 1) v += __shfl_xor(v, m, 64);
            if ((tid & 63) == 0) red[tid >> 6] = v;
            __syncthreads();
            float Z = 0.0f;
            #pragma unroll
            for (int wv = 0; wv < NWAVE; ++wv) Z += red[wv];
            ll += logf(Z);
            a *= (1.0f / Z);
        }
    }

    // final residual mass (steps since last renorm)
    {
        float v = act ? a : 0.0f;
        #pragma unroll
        for (int m = 32; m >= 1; m >>= 1) v += __shfl_xor(v, m, 64);
        if ((tid & 63) == 0) red[tid >> 6] = v;
        __syncthreads();
        float Z = 0.0f;
        #pragma unroll
        for (int wv = 0; wv < NWAVE; ++wv) Z += red[wv];
        ll += logf(Z);
    }
    if (tid == 0) out[b] = ll;
}

extern "C" void kernel_launch(void* const* d_in, const int* in_sizes, int n_in,
                              void* d_out, int out_size, void* d_ws, size_t ws_size,
                              hipStream_t stream)
{
    const float* x  = (const float*)d_in[0];   // inputs [32,8192,101]
    const float* ik = (const float*)d_in[1];   // init_kernel [4]
    const float* tk = (const float*)d_in[2];   // transition_kernel [1836]
    const float* ek = (const float*)d_in[3];   // emission_kernel [58656]
    float* out = (float*)d_out;

    char* ws = (char*)d_ws;
    float* wIn   = (float*)(ws + WIN_OFF);
    float* Ivec  = (float*)(ws + IV_OFF);
    float* emisT = (float*)(ws + EMIS_OFF);
    int*   obs   = (int*)(ws + OBS_OFF);

    hipLaunchKernelGGL(prep_tables, dim3(3), dim3(256), 0, stream, tk, ik, wIn, Ivec);
    hipLaunchKernelGGL(prep_emis, dim3((100*S + 255)/256), dim3(256), 0, stream, ek, emisT);
    hipLaunchKernelGGL(extract_obs, dim3((NB*TT + 3)/4), dim3(256), 0, stream, x, obs);
    hipLaunchKernelGGL(forward, dim3(NB), dim3(BS), 0, stream, emisT, wIn, Ivec, obs, out);
}

// Round 2
// 2590.852 us; speedup vs baseline: 1.1806x; 1.1806x over previous
//
#include <hip/hip_runtime.h>
#include <math.h>

#define S    612
#define SP   640          // padded state count (64 lanes x 10)
#define TT   8192
#define NB   32

// workspace layout (bytes)
#define WIN_OFF   0        // 640 float4 = 10240 B
#define IV_OFF    10240    // 4 floats
#define EMIS_OFF  16384    // 100*640 floats = 256000 B
#define OBS_OFF   272384   // 32*8192 ints = 1 MB  (16B aligned)

__global__ __launch_bounds__(256) void prep_tables(
    const float* __restrict__ tk, const float* __restrict__ ik,
    float* __restrict__ wIn2, float* __restrict__ Ivec)
{
    int i = blockIdx.x * 256 + threadIdx.x;
    if (i < S) {
        float l0 = tk[3*i], l1 = tk[3*i+1], l2 = tk[3*i+2], l3 = 1.0f;
        float m = fmaxf(fmaxf(l0, l1), fmaxf(l2, l3));
        float e0 = expf(l0-m), e1 = expf(l1-m), e2 = expf(l2-m), e3 = expf(l3-m);
        float inv = 1.0f / (e0+e1+e2+e3);
        // incoming layout: wIn2[(i+j)%S][j] = p_i[j]
        wIn2[4*i + 0]              = e0*inv;
        wIn2[4*((i+1)%S) + 1]      = e1*inv;
        wIn2[4*((i+2)%S) + 2]      = e2*inv;
        wIn2[4*((i+3)%S) + 3]      = e3*inv;
    } else if (i < SP) {
        // zero the padded states (ws is poisoned 0xAA by the harness)
        wIn2[4*i+0] = 0.f; wIn2[4*i+1] = 0.f; wIn2[4*i+2] = 0.f; wIn2[4*i+3] = 0.f;
    } else if (i == SP) {
        float l0 = ik[0], l1 = ik[1], l2 = ik[2], l3 = ik[3];
        float m = fmaxf(fmaxf(l0,l1), fmaxf(l2,l3));
        float e0 = expf(l0-m), e1 = expf(l1-m), e2 = expf(l2-m), e3 = expf(l3-m);
        float inv = 1.0f / (e0+e1+e2+e3);
        Ivec[0]=e0*inv; Ivec[1]=e1*inv; Ivec[2]=e2*inv; Ivec[3]=e3*inv;
    }
}

__global__ __launch_bounds__(256) void prep_emis(
    const float* __restrict__ ek, float* __restrict__ emisP)
{
    int tid = blockIdx.x * 256 + threadIdx.x;       // tid = o*SP + s
    if (tid >= 100*SP) return;
    int s = tid % SP;
    int o = tid / SP;
    float val = 0.0f;
    if (s < S-1) {
        int c = o >> 2, l = o & 3;
        if (c == 0) {
            val = 0.25f;
        } else {
            const float* g = ek + s*96 + (c-1)*4;
            float a0=g[0], a1=g[1], a2=g[2], a3=g[3];
            float m = fmaxf(fmaxf(a0,a1), fmaxf(a2,a3));
            float x0=expf(a0-m), x1=expf(a1-m), x2=expf(a2-m), x3=expf(a3-m);
            float inv = 1.0f/(x0+x1+x2+x3);
            float sel = (l==0)?x0:(l==1)?x1:(l==2)?x2:x3;
            val = sel * inv;
        }
    }
    emisP[tid] = val;   // emisP[o][s], s-fastest, padded to 640
}

// one wave per one-hot row: o = round(dot(row, iota))
__global__ __launch_bounds__(256) void extract_obs(
    const float* __restrict__ x, int* __restrict__ obs)
{
    int row  = blockIdx.x * 4 + (threadIdx.x >> 6);
    int lane = threadIdx.x & 63;
    if (row >= NB*TT) return;
    const float* r = x + (size_t)row * 101;
    float acc = r[lane] * (float)lane;
    if (lane < 37) acc += r[64 + lane] * (float)(64 + lane);
    #pragma unroll
    for (int m = 32; m >= 1; m >>= 1) acc += __shfl_xor(acc, m, 64);
    if (lane == 0) obs[row] = (int)(acc + 0.5f);
}

// one wave per batch: lane l owns states 10l..10l+9; no barriers in the T loop
__global__ __launch_bounds__(64) void forward(
    const float* __restrict__ emisP, const float4* __restrict__ wIn2,
    const float* __restrict__ Ivec, const int* __restrict__ obs,
    float* __restrict__ out)
{
    __shared__ int obs_s[TT];
    const int l = threadIdx.x;
    const int b = blockIdx.x;

    {
        const int4* osrc = (const int4*)(obs + b*TT);
        int4* odst = (int4*)obs_s;
        #pragma unroll
        for (int i = 0; i < TT/4/64; ++i) odst[l + 64*i] = osrc[l + 64*i];
    }
    __syncthreads();

    float4 w[10];
    #pragma unroll
    for (int k = 0; k < 10; ++k) w[k] = wIn2[10*l + k];

    float a[10];
    float ll = 0.0f;

    // t = 0
    {
        int o0 = obs_s[0];
        #pragma unroll
        for (int k = 0; k < 10; ++k) {
            int s = 10*l + k;
            float Iv = (s < 4) ? Ivec[s] : 0.0f;
            a[k] = emisP[o0*SP + s] * Iv;
        }
        float z = ((a[0]+a[1])+(a[2]+a[3])) + ((a[4]+a[5])+(a[6]+a[7])) + (a[8]+a[9]);
        #pragma unroll
        for (int m = 32; m >= 1; m >>= 1) z += __shfl_xor(z, m, 64);
        ll = logf(z);
        float inv = 1.0f/z;
        #pragma unroll
        for (int k = 0; k < 10; ++k) a[k] *= inv;
    }

    // prefetch emission rows for t=1 (bufA) and t=2 (bufB)
    float2 bA[5], bB[5];
    {
        const float2* p1 = (const float2*)(emisP + obs_s[1]*SP + 10*l);
        #pragma unroll
        for (int k = 0; k < 5; ++k) bA[k] = p1[k];
        const float2* p2 = (const float2*)(emisP + obs_s[2]*SP + 10*l);
        #pragma unroll
        for (int k = 0; k < 5; ++k) bB[k] = p2[k];
    }

    auto stepf = [&](float2 (&buf)[5], int t) {
        float e[10];
        #pragma unroll
        for (int k = 0; k < 5; ++k) { e[2*k] = buf[k].x; e[2*k+1] = buf[k].y; }
        if (t + 2 < TT) {   // reload this buffer for step t+2 (prefetch distance 2)
            int o2 = obs_s[t+2];
            const float2* src = (const float2*)(emisP + o2*SP + 10*l);
            #pragma unroll
            for (int k = 0; k < 5; ++k) buf[k] = src[k];
        }
        float pm1 = __shfl_up(a[9], 1, 64);
        float pm2 = __shfl_up(a[8], 1, 64);
        float pm3 = __shfl_up(a[7], 1, 64);
        float v609 = __shfl(a[9], 60, 64);   // state 609 (lane 60 reg 9)
        float v610 = __shfl(a[0], 61, 64);   // state 610 (lane 61 reg 0)
        float v611 = __shfl(a[1], 61, 64);   // state 611 (lane 61 reg 1)
        if (l == 0) { pm1 = v611; pm2 = v610; pm3 = v609; }
        float n[10];
        n[0] = e[0]*(a[0]*w[0].x + pm1*w[0].y + pm2*w[0].z + pm3*w[0].w);
        n[1] = e[1]*(a[1]*w[1].x + a[0]*w[1].y + pm1*w[1].z + pm2*w[1].w);
        n[2] = e[2]*(a[2]*w[2].x + a[1]*w[2].y + a[0]*w[2].z + pm1*w[2].w);
        #pragma unroll
        for (int k = 3; k < 10; ++k)
            n[k] = e[k]*(a[k]*w[k].x + a[k-1]*w[k].y + a[k-2]*w[k].z + a[k-3]*w[k].w);
        #pragma unroll
        for (int k = 0; k < 10; ++k) a[k] = n[k];
        if ((t & 7) == 0) {   // renorm every 8 steps
            float z = ((a[0]+a[1])+(a[2]+a[3])) + ((a[4]+a[5])+(a[6]+a[7])) + (a[8]+a[9]);
            #pragma unroll
            for (int m = 32; m >= 1; m >>= 1) z += __shfl_xor(z, m, 64);
            ll += logf(z);
            float inv = 1.0f/z;
            #pragma unroll
            for (int k = 0; k < 10; ++k) a[k] *= inv;
        }
    };

    for (int t = 1; t < TT; t += 2) {
        stepf(bA, t);
        if (t + 1 < TT) stepf(bB, t + 1);
    }

    // residual mass since last renorm
    {
        float z = ((a[0]+a[1])+(a[2]+a[3])) + ((a[4]+a[5])+(a[6]+a[7])) + (a[8]+a[9]);
        #pragma unroll
        for (int m = 32; m >= 1; m >>= 1) z += __shfl_xor(z, m, 64);
        ll += logf(z);
    }
    if (l == 0) out[b] = ll;
}

extern "C" void kernel_launch(void* const* d_in, const int* in_sizes, int n_in,
                              void* d_out, int out_size, void* d_ws, size_t ws_size,
                              hipStream_t stream)
{
    const float* x  = (const float*)d_in[0];   // inputs [32,8192,101]
    const float* ik = (const float*)d_in[1];   // init_kernel [4]
    const float* tk = (const float*)d_in[2];   // transition_kernel [1836]
    const float* ek = (const float*)d_in[3];   // emission_kernel [58656]
    float* out = (float*)d_out;

    char* ws = (char*)d_ws;
    float*  wIn2  = (float*)(ws + WIN_OFF);
    float*  Ivec  = (float*)(ws + IV_OFF);
    float*  emisP = (float*)(ws + EMIS_OFF);
    int*    obs   = (int*)(ws + OBS_OFF);

    hipLaunchKernelGGL(prep_tables, dim3(3), dim3(256), 0, stream, tk, ik, wIn2, Ivec);
    hipLaunchKernelGGL(prep_emis, dim3((100*SP + 255)/256), dim3(256), 0, stream, ek, emisP);
    hipLaunchKernelGGL(extract_obs, dim3((NB*TT + 3)/4), dim3(256), 0, stream, x, obs);
    hipLaunchKernelGGL(forward, dim3(NB), dim3(64), 0, stream,
                       emisP, (const float4*)wIn2, Ivec, obs, out);
}

// Round 3
// 1630.248 us; speedup vs baseline: 1.8762x; 1.5892x over previous
//
#include <hip/hip_runtime.h>
#include <math.h>

#define S    612
#define SP   640          // padded state count (64 lanes x 10)
#define TT   8192
#define NB   32
#define NGROUPS 1023      // groups cover steps 1..8184; epilogue 8185..8191

// workspace layout (bytes)
#define WIN_OFF   0        // 640 float4 = 10240 B
#define IV_OFF    10240    // 4 floats
#define EMIS_OFF  16384    // 100*640 floats = 256000 B
#define OBS_OFF   272384   // 32*8192 ints = 1 MB  (16B aligned)

__global__ __launch_bounds__(256) void prep_tables(
    const float* __restrict__ tk, const float* __restrict__ ik,
    float* __restrict__ wIn2, float* __restrict__ Ivec)
{
    int i = blockIdx.x * 256 + threadIdx.x;
    if (i < S) {
        float l0 = tk[3*i], l1 = tk[3*i+1], l2 = tk[3*i+2], l3 = 1.0f;
        float m = fmaxf(fmaxf(l0, l1), fmaxf(l2, l3));
        float e0 = expf(l0-m), e1 = expf(l1-m), e2 = expf(l2-m), e3 = expf(l3-m);
        float inv = 1.0f / (e0+e1+e2+e3);
        wIn2[4*i + 0]              = e0*inv;
        wIn2[4*((i+1)%S) + 1]      = e1*inv;
        wIn2[4*((i+2)%S) + 2]      = e2*inv;
        wIn2[4*((i+3)%S) + 3]      = e3*inv;
    } else if (i < SP) {
        wIn2[4*i+0] = 0.f; wIn2[4*i+1] = 0.f; wIn2[4*i+2] = 0.f; wIn2[4*i+3] = 0.f;
    } else if (i == SP) {
        float l0 = ik[0], l1 = ik[1], l2 = ik[2], l3 = ik[3];
        float m = fmaxf(fmaxf(l0,l1), fmaxf(l2,l3));
        float e0 = expf(l0-m), e1 = expf(l1-m), e2 = expf(l2-m), e3 = expf(l3-m);
        float inv = 1.0f / (e0+e1+e2+e3);
        Ivec[0]=e0*inv; Ivec[1]=e1*inv; Ivec[2]=e2*inv; Ivec[3]=e3*inv;
    }
}

__global__ __launch_bounds__(256) void prep_emis(
    const float* __restrict__ ek, float* __restrict__ emisP)
{
    int tid = blockIdx.x * 256 + threadIdx.x;       // tid = o*SP + s
    if (tid >= 100*SP) return;
    int s = tid % SP;
    int o = tid / SP;
    float val = 0.0f;
    if (s < S-1) {
        int c = o >> 2, l = o & 3;
        if (c == 0) {
            val = 0.25f;
        } else {
            const float* g = ek + s*96 + (c-1)*4;
            float a0=g[0], a1=g[1], a2=g[2], a3=g[3];
            float m = fmaxf(fmaxf(a0,a1), fmaxf(a2,a3));
            float x0=expf(a0-m), x1=expf(a1-m), x2=expf(a2-m), x3=expf(a3-m);
            float inv = 1.0f/(x0+x1+x2+x3);
            float sel = (l==0)?x0:(l==1)?x1:(l==2)?x2:x3;
            val = sel * inv;
        }
    }
    emisP[tid] = val;
}

__global__ __launch_bounds__(256) void extract_obs(
    const float* __restrict__ x, int* __restrict__ obs)
{
    int row  = blockIdx.x * 4 + (threadIdx.x >> 6);
    int lane = threadIdx.x & 63;
    if (row >= NB*TT) return;
    const float* r = x + (size_t)row * 101;
    float acc = r[lane] * (float)lane;
    if (lane < 37) acc += r[64 + lane] * (float)(64 + lane);
    #pragma unroll
    for (int m = 32; m >= 1; m >>= 1) acc += __shfl_xor(acc, m, 64);
    if (lane == 0) obs[row] = (int)(acc + 0.5f);
}

// emission value K (0..9) of rotating buffer JB — all indices compile-time
#define EVQ(JB,K) (((K)&1) ? eb[JB][(K)>>1].y : eb[JB][(K)>>1].x)

// one HMM step consuming emission expressions E0..E9
#define HMM_CORE(E0,E1,E2,E3,E4,E5,E6,E7,E8,E9)                              \
  {                                                                          \
    float pm1 = __shfl_up(a[9], 1, 64);                                      \
    float pm2 = __shfl_up(a[8], 1, 64);                                      \
    float pm3 = __shfl_up(a[7], 1, 64);                                      \
    float v609 = __shfl(a[9], 60, 64);                                       \
    float v610 = __shfl(a[0], 61, 64);                                       \
    float v611 = __shfl(a[1], 61, 64);                                       \
    if (l == 0) { pm1 = v611; pm2 = v610; pm3 = v609; }                      \
    float n0 = (E0)*(a[0]*w[0].x + pm1 *w[0].y + pm2 *w[0].z + pm3 *w[0].w); \
    float n1 = (E1)*(a[1]*w[1].x + a[0]*w[1].y + pm1 *w[1].z + pm2 *w[1].w); \
    float n2 = (E2)*(a[2]*w[2].x + a[1]*w[2].y + a[0]*w[2].z + pm1 *w[2].w); \
    float n3 = (E3)*(a[3]*w[3].x + a[2]*w[3].y + a[1]*w[3].z + a[0]*w[3].w); \
    float n4 = (E4)*(a[4]*w[4].x + a[3]*w[4].y + a[2]*w[4].z + a[1]*w[4].w); \
    float n5 = (E5)*(a[5]*w[5].x + a[4]*w[5].y + a[3]*w[5].z + a[2]*w[5].w); \
    float n6 = (E6)*(a[6]*w[6].x + a[5]*w[6].y + a[4]*w[6].z + a[3]*w[6].w); \
    float n7 = (E7)*(a[7]*w[7].x + a[6]*w[7].y + a[5]*w[7].z + a[4]*w[7].w); \
    float n8 = (E8)*(a[8]*w[8].x + a[7]*w[8].y + a[6]*w[8].z + a[5]*w[8].w); \
    float n9 = (E9)*(a[9]*w[9].x + a[8]*w[9].y + a[7]*w[9].z + a[6]*w[9].w); \
    a[0]=n0; a[1]=n1; a[2]=n2; a[3]=n3; a[4]=n4;                             \
    a[5]=n5; a[6]=n6; a[7]=n7; a[8]=n8; a[9]=n9;                             \
  }

#define HMM_STEP(JB) HMM_CORE(EVQ(JB,0),EVQ(JB,1),EVQ(JB,2),EVQ(JB,3),       \
                              EVQ(JB,4),EVQ(JB,5),EVQ(JB,6),EVQ(JB,7),       \
                              EVQ(JB,8),EVQ(JB,9))

// refill rotating buffer JB with emission row for (wave-uniform) obs OBSV
#define PREFETCH(JB, OBSV)                                                   \
  { int _oo = __builtin_amdgcn_readfirstlane(OBSV);                          \
    const float2* _p = (const float2*)(emisP + _oo*SP + 10*l);               \
    eb[JB][0]=_p[0]; eb[JB][1]=_p[1]; eb[JB][2]=_p[2];                       \
    eb[JB][3]=_p[3]; eb[JB][4]=_p[4]; }

#define LOCSUM() (((a[0]+a[1])+(a[2]+a[3])) + ((a[4]+a[5])+(a[6]+a[7])) + (a[8]+a[9]))

// one wave per batch: lane l owns states 10l..10l+9; zero barriers in the T loop
__global__ __launch_bounds__(64) void forward(
    const float* __restrict__ emisP, const float4* __restrict__ wIn2,
    const float* __restrict__ Ivec, const int* __restrict__ obs,
    float* __restrict__ out)
{
    __shared__ int obs_s[TT + 16];
    const int l = threadIdx.x;
    const int b = blockIdx.x;

    {
        const int4* osrc = (const int4*)(obs + b*TT);
        int4* odst = (int4*)obs_s;
        #pragma unroll
        for (int i = 0; i < TT/4/64; ++i) odst[l + 64*i] = osrc[l + 64*i];
        if (l < 4) odst[TT/4 + l] = make_int4(0,0,0,0);   // zero pad obs_s[8192..8207]
    }
    __syncthreads();

    float4 w[10];
    #pragma unroll
    for (int k = 0; k < 10; ++k) w[k] = wIn2[10*l + k];

    float a[10];
    float ll = 0.0f;

    // t = 0
    {
        int o0 = obs_s[0];
        const float* er = emisP + o0*SP + 10*l;
        #pragma unroll
        for (int k = 0; k < 10; ++k) {
            int s = 10*l + k;
            float Iv = (s < 4) ? Ivec[s] : 0.0f;
            a[k] = er[k] * Iv;
        }
    }
    float zl = LOCSUM();   // z_0 partial; butterfly runs inside group 0

    int oc[8], on[8];
    #pragma unroll
    for (int i = 0; i < 8; ++i) oc[i] = obs_s[1 + i];   // obs for steps 1..8
    #pragma unroll
    for (int i = 0; i < 8; ++i) on[i] = obs_s[9 + i];   // obs for steps 9..16

    float2 eb[4][5];
    #pragma unroll
    for (int j = 0; j < 4; ++j) {
        int oo = __builtin_amdgcn_readfirstlane(oc[j]);
        const float2* p = (const float2*)(emisP + oo*SP + 10*l);
        #pragma unroll
        for (int q = 0; q < 5; ++q) eb[j][q] = p[q];
    }

    for (int g = 0; g < NGROUPS; ++g) {
        // steps 8g+1 .. 8g+8 ; butterfly of z_{8g} spread over steps 1..6;
        // fold 1/z into the boundary step's emission (linearity of the recurrence)
        HMM_STEP(0); PREFETCH(0, oc[4]);
        zl += __shfl_xor(zl, 32, 64);
        HMM_STEP(1); PREFETCH(1, oc[5]);
        zl += __shfl_xor(zl, 16, 64);
        HMM_STEP(2); PREFETCH(2, oc[6]);
        zl += __shfl_xor(zl, 8, 64);
        HMM_STEP(3); PREFETCH(3, oc[7]);
        zl += __shfl_xor(zl, 4, 64);
        HMM_STEP(0); PREFETCH(0, on[0]);
        zl += __shfl_xor(zl, 2, 64);
        HMM_STEP(1); PREFETCH(1, on[1]);
        zl += __shfl_xor(zl, 1, 64);
        float z   = zl;
        float inv = 1.0f / z;
        float lg  = logf(z);
        HMM_STEP(2); PREFETCH(2, on[2]);
        float ep[10];
        #pragma unroll
        for (int k = 0; k < 10; ++k) ep[k] = EVQ(3,k) * inv;
        HMM_CORE(ep[0],ep[1],ep[2],ep[3],ep[4],ep[5],ep[6],ep[7],ep[8],ep[9]);
        PREFETCH(3, on[3]);
        ll += lg;
        zl = LOCSUM();
        #pragma unroll
        for (int i = 0; i < 8; ++i) oc[i] = on[i];
        int base = 8*g + 17;
        #pragma unroll
        for (int i = 0; i < 8; ++i) on[i] = obs_s[base + i];
    }

    // epilogue: steps 8185..8191 (no renorm; final sum captures the residual scale)
    HMM_STEP(0); PREFETCH(0, oc[4]);
    HMM_STEP(1); PREFETCH(1, oc[5]);
    HMM_STEP(2); PREFETCH(2, oc[6]);
    HMM_STEP(3);
    HMM_STEP(0);
    HMM_STEP(1);
    HMM_STEP(2);

    {
        float zf = LOCSUM();
        #pragma unroll
        for (int m = 32; m >= 1; m >>= 1) zf += __shfl_xor(zf, m, 64);
        ll += logf(zf);
    }
    if (l == 0) out[b] = ll;
}

extern "C" void kernel_launch(void* const* d_in, const int* in_sizes, int n_in,
                              void* d_out, int out_size, void* d_ws, size_t ws_size,
                              hipStream_t stream)
{
    const float* x  = (const float*)d_in[0];   // inputs [32,8192,101]
    const float* ik = (const float*)d_in[1];   // init_kernel [4]
    const float* tk = (const float*)d_in[2];   // transition_kernel [1836]
    const float* ek = (const float*)d_in[3];   // emission_kernel [58656]
    float* out = (float*)d_out;

    char* ws = (char*)d_ws;
    float*  wIn2  = (float*)(ws + WIN_OFF);
    float*  Ivec  = (float*)(ws + IV_OFF);
    float*  emisP = (float*)(ws + EMIS_OFF);
    int*    obs   = (int*)(ws + OBS_OFF);

    hipLaunchKernelGGL(prep_tables, dim3(3), dim3(256), 0, stream, tk, ik, wIn2, Ivec);
    hipLaunchKernelGGL(prep_emis, dim3((100*SP + 255)/256), dim3(256), 0, stream, ek, emisP);
    hipLaunchKernelGGL(extract_obs, dim3((NB*TT + 3)/4), dim3(256), 0, stream, x, obs);
    hipLaunchKernelGGL(forward, dim3(NB), dim3(64), 0, stream,
                       emisP, (const float4*)wIn2, Ivec, obs, out);
}

// Round 4
// 1408.800 us; speedup vs baseline: 2.1711x; 1.1572x over previous
//
#include <hip/hip_runtime.h>
#include <math.h>

#define S    612
#define SP   640          // padded state count (64 lanes x 10)
#define TT   8192
#define NB   32
#define NGROUPS 1023      // groups cover steps 1..8184; epilogue 8185..8191

// workspace layout (bytes)
#define WIN_OFF   0        // 640 float4 = 10240 B
#define IV_OFF    10240    // 4 floats
#define EMIS_OFF  16384    // 100*640 floats = 256000 B
#define OBS_OFF   272384   // 32*8192 ints = 1 MB  (16B aligned)

__global__ __launch_bounds__(256) void prep_tables(
    const float* __restrict__ tk, const float* __restrict__ ik,
    float* __restrict__ wIn2, float* __restrict__ Ivec)
{
    int i = blockIdx.x * 256 + threadIdx.x;
    if (i < S) {
        float l0 = tk[3*i], l1 = tk[3*i+1], l2 = tk[3*i+2], l3 = 1.0f;
        float m = fmaxf(fmaxf(l0, l1), fmaxf(l2, l3));
        float e0 = expf(l0-m), e1 = expf(l1-m), e2 = expf(l2-m), e3 = expf(l3-m);
        float inv = 1.0f / (e0+e1+e2+e3);
        wIn2[4*i + 0]              = e0*inv;
        wIn2[4*((i+1)%S) + 1]      = e1*inv;
        wIn2[4*((i+2)%S) + 2]      = e2*inv;
        wIn2[4*((i+3)%S) + 3]      = e3*inv;
    } else if (i < SP) {
        wIn2[4*i+0] = 0.f; wIn2[4*i+1] = 0.f; wIn2[4*i+2] = 0.f; wIn2[4*i+3] = 0.f;
    } else if (i == SP) {
        float l0 = ik[0], l1 = ik[1], l2 = ik[2], l3 = ik[3];
        float m = fmaxf(fmaxf(l0,l1), fmaxf(l2,l3));
        float e0 = expf(l0-m), e1 = expf(l1-m), e2 = expf(l2-m), e3 = expf(l3-m);
        float inv = 1.0f / (e0+e1+e2+e3);
        Ivec[0]=e0*inv; Ivec[1]=e1*inv; Ivec[2]=e2*inv; Ivec[3]=e3*inv;
    }
}

__global__ __launch_bounds__(256) void prep_emis(
    const float* __restrict__ ek, float* __restrict__ emisP)
{
    int tid = blockIdx.x * 256 + threadIdx.x;       // tid = o*SP + s
    if (tid >= 100*SP) return;
    int s = tid % SP;
    int o = tid / SP;
    float val = 0.0f;
    if (s < S-1) {
        int c = o >> 2, l = o & 3;
        if (c == 0) {
            val = 0.25f;
        } else {
            const float* g = ek + s*96 + (c-1)*4;
            float a0=g[0], a1=g[1], a2=g[2], a3=g[3];
            float m = fmaxf(fmaxf(a0,a1), fmaxf(a2,a3));
            float x0=expf(a0-m), x1=expf(a1-m), x2=expf(a2-m), x3=expf(a3-m);
            float inv = 1.0f/(x0+x1+x2+x3);
            float sel = (l==0)?x0:(l==1)?x1:(l==2)?x2:x3;
            val = sel * inv;
        }
    }
    emisP[tid] = val;
}

__global__ __launch_bounds__(256) void extract_obs(
    const float* __restrict__ x, int* __restrict__ obs)
{
    int row  = blockIdx.x * 4 + (threadIdx.x >> 6);
    int lane = threadIdx.x & 63;
    if (row >= NB*TT) return;
    const float* r = x + (size_t)row * 101;
    float acc = r[lane] * (float)lane;
    if (lane < 37) acc += r[64 + lane] * (float)(64 + lane);
    #pragma unroll
    for (int m = 32; m >= 1; m >>= 1) acc += __shfl_xor(acc, m, 64);
    if (lane == 0) obs[row] = (int)(acc + 0.5f);
}

// lane-shift-up-by-1 via DPP wave_shr:1 (VALU pipe, no DS latency); lane 0 -> 0
__device__ __forceinline__ float dpp_up1(float x) {
    int xi = __builtin_bit_cast(int, x);
    int r = __builtin_amdgcn_update_dpp(0, xi, 0x138, 0xF, 0xF, true);
    return __builtin_bit_cast(float, r);
}
// uniform broadcast of a fixed lane via v_readlane (SALU path)
__device__ __forceinline__ float rdlane(float x, int lane) {
    return __builtin_bit_cast(float, __builtin_amdgcn_readlane(__builtin_bit_cast(int, x), lane));
}

// emission value K (0..9) of rotating buffer JB — all indices compile-time
#define EVQ(JB,K) (((K)&1) ? eb[JB][(K)>>1].y : eb[JB][(K)>>1].x)

// one HMM step consuming emission expressions E0..E9.
// cross-lane via DPP (VALU) + readlane wrap (SALU); n3..n9 first for scheduling.
#define HMM_CORE(E0,E1,E2,E3,E4,E5,E6,E7,E8,E9)                              \
  {                                                                          \
    float pm1 = dpp_up1(a[9]);                                               \
    float pm2 = dpp_up1(a[8]);                                               \
    float pm3 = dpp_up1(a[7]);                                               \
    float v609 = rdlane(a[9], 60);                                           \
    float v610 = rdlane(a[0], 61);                                           \
    float v611 = rdlane(a[1], 61);                                           \
    pm1 = isl0 ? v611 : pm1;                                                 \
    pm2 = isl0 ? v610 : pm2;                                                 \
    pm3 = isl0 ? v609 : pm3;                                                 \
    float n3 = (E3)*(a[3]*w[3].x + a[2]*w[3].y + a[1]*w[3].z + a[0]*w[3].w); \
    float n4 = (E4)*(a[4]*w[4].x + a[3]*w[4].y + a[2]*w[4].z + a[1]*w[4].w); \
    float n5 = (E5)*(a[5]*w[5].x + a[4]*w[5].y + a[3]*w[5].z + a[2]*w[5].w); \
    float n6 = (E6)*(a[6]*w[6].x + a[5]*w[6].y + a[4]*w[6].z + a[3]*w[6].w); \
    float n7 = (E7)*(a[7]*w[7].x + a[6]*w[7].y + a[5]*w[7].z + a[4]*w[7].w); \
    float n8 = (E8)*(a[8]*w[8].x + a[7]*w[8].y + a[6]*w[8].z + a[5]*w[8].w); \
    float n9 = (E9)*(a[9]*w[9].x + a[8]*w[9].y + a[7]*w[9].z + a[6]*w[9].w); \
    float n0 = (E0)*(a[0]*w[0].x + pm1 *w[0].y + pm2 *w[0].z + pm3 *w[0].w); \
    float n1 = (E1)*(a[1]*w[1].x + a[0]*w[1].y + pm1 *w[1].z + pm2 *w[1].w); \
    float n2 = (E2)*(a[2]*w[2].x + a[1]*w[2].y + a[0]*w[2].z + pm1 *w[2].w); \
    a[0]=n0; a[1]=n1; a[2]=n2; a[3]=n3; a[4]=n4;                             \
    a[5]=n5; a[6]=n6; a[7]=n7; a[8]=n8; a[9]=n9;                             \
  }

#define HMM_STEP(JB) HMM_CORE(EVQ(JB,0),EVQ(JB,1),EVQ(JB,2),EVQ(JB,3),       \
                              EVQ(JB,4),EVQ(JB,5),EVQ(JB,6),EVQ(JB,7),       \
                              EVQ(JB,8),EVQ(JB,9))

// refill rotating buffer JB with emission row for (wave-uniform) obs OBSV
#define PREFETCH(JB, OBSV)                                                   \
  { int _oo = __builtin_amdgcn_readfirstlane(OBSV);                          \
    const float2* _p = (const float2*)(emisP + _oo*SP + 10*l);               \
    eb[JB][0]=_p[0]; eb[JB][1]=_p[1]; eb[JB][2]=_p[2];                       \
    eb[JB][3]=_p[3]; eb[JB][4]=_p[4]; }

#define LOCSUM() (((a[0]+a[1])+(a[2]+a[3])) + ((a[4]+a[5])+(a[6]+a[7])) + (a[8]+a[9]))

// one wave per batch: lane l owns states 10l..10l+9; zero barriers in the T loop
__global__ __launch_bounds__(64) void forward(
    const float* __restrict__ emisP, const float4* __restrict__ wIn2,
    const float* __restrict__ Ivec, const int* __restrict__ obs,
    float* __restrict__ out)
{
    __shared__ int obs_s[TT + 16];
    const int l = threadIdx.x;
    const int b = blockIdx.x;
    const bool isl0 = (l == 0);

    {
        const int4* osrc = (const int4*)(obs + b*TT);
        int4* odst = (int4*)obs_s;
        #pragma unroll
        for (int i = 0; i < TT/4/64; ++i) odst[l + 64*i] = osrc[l + 64*i];
        if (l < 4) odst[TT/4 + l] = make_int4(0,0,0,0);
    }
    __syncthreads();

    float4 w[10];
    #pragma unroll
    for (int k = 0; k < 10; ++k) w[k] = wIn2[10*l + k];

    float a[10];
    float ll = 0.0f;

    // t = 0
    {
        int o0 = obs_s[0];
        const float* er = emisP + o0*SP + 10*l;
        #pragma unroll
        for (int k = 0; k < 10; ++k) {
            int s = 10*l + k;
            float Iv = (s < 4) ? Ivec[s] : 0.0f;
            a[k] = er[k] * Iv;
        }
    }
    float zl = LOCSUM();   // z_0 partial; butterfly runs inside group 0

    int oc[8], on[8];
    #pragma unroll
    for (int i = 0; i < 8; ++i) oc[i] = obs_s[1 + i];
    #pragma unroll
    for (int i = 0; i < 8; ++i) on[i] = obs_s[9 + i];

    float2 eb[4][5];
    #pragma unroll
    for (int j = 0; j < 4; ++j) {
        int oo = __builtin_amdgcn_readfirstlane(oc[j]);
        const float2* p = (const float2*)(emisP + oo*SP + 10*l);
        #pragma unroll
        for (int q = 0; q < 5; ++q) eb[j][q] = p[q];
    }

    for (int g = 0; g < NGROUPS; ++g) {
        // steps 8g+1 .. 8g+8 ; butterfly of z_{8g} spread over steps 1..6;
        // fold 1/z into the boundary step's emission (linearity of the recurrence)
        HMM_STEP(0); PREFETCH(0, oc[4]);
        zl += __shfl_xor(zl, 32, 64);
        HMM_STEP(1); PREFETCH(1, oc[5]);
        zl += __shfl_xor(zl, 16, 64);
        HMM_STEP(2); PREFETCH(2, oc[6]);
        zl += __shfl_xor(zl, 8, 64);
        HMM_STEP(3); PREFETCH(3, oc[7]);
        zl += __shfl_xor(zl, 4, 64);
        HMM_STEP(0); PREFETCH(0, on[0]);
        zl += __shfl_xor(zl, 2, 64);
        HMM_STEP(1); PREFETCH(1, on[1]);
        zl += __shfl_xor(zl, 1, 64);
        float z   = zl;
        float inv = __builtin_amdgcn_rcpf(z);   // error self-corrected by next z
        float lg  = logf(z);
        HMM_STEP(2); PREFETCH(2, on[2]);
        float ep[10];
        #pragma unroll
        for (int k = 0; k < 10; ++k) ep[k] = EVQ(3,k) * inv;
        HMM_CORE(ep[0],ep[1],ep[2],ep[3],ep[4],ep[5],ep[6],ep[7],ep[8],ep[9]);
        PREFETCH(3, on[3]);
        ll += lg;
        zl = LOCSUM();
        #pragma unroll
        for (int i = 0; i < 8; ++i) oc[i] = on[i];
        int base = 8*g + 17;
        #pragma unroll
        for (int i = 0; i < 8; ++i) on[i] = obs_s[base + i];
    }

    // epilogue: steps 8185..8191 (no renorm; final sum captures the residual scale)
    HMM_STEP(0); PREFETCH(0, oc[4]);
    HMM_STEP(1); PREFETCH(1, oc[5]);
    HMM_STEP(2); PREFETCH(2, oc[6]);
    HMM_STEP(3);
    HMM_STEP(0);
    HMM_STEP(1);
    HMM_STEP(2);

    {
        float zf = LOCSUM();
        #pragma unroll
        for (int m = 32; m >= 1; m >>= 1) zf += __shfl_xor(zf, m, 64);
        ll += logf(zf);
    }
    if (l == 0) out[b] = ll;
}

extern "C" void kernel_launch(void* const* d_in, const int* in_sizes, int n_in,
                              void* d_out, int out_size, void* d_ws, size_t ws_size,
                              hipStream_t stream)
{
    const float* x  = (const float*)d_in[0];   // inputs [32,8192,101]
    const float* ik = (const float*)d_in[1];   // init_kernel [4]
    const float* tk = (const float*)d_in[2];   // transition_kernel [1836]
    const float* ek = (const float*)d_in[3];   // emission_kernel [58656]
    float* out = (float*)d_out;

    char* ws = (char*)d_ws;
    float*  wIn2  = (float*)(ws + WIN_OFF);
    float*  Ivec  = (float*)(ws + IV_OFF);
    float*  emisP = (float*)(ws + EMIS_OFF);
    int*    obs   = (int*)(ws + OBS_OFF);

    hipLaunchKernelGGL(prep_tables, dim3(3), dim3(256), 0, stream, tk, ik, wIn2, Ivec);
    hipLaunchKernelGGL(prep_emis, dim3((100*SP + 255)/256), dim3(256), 0, stream, ek, emisP);
    hipLaunchKernelGGL(extract_obs, dim3((NB*TT + 3)/4), dim3(256), 0, stream, x, obs);
    hipLaunchKernelGGL(forward, dim3(NB), dim3(64), 0, stream,
                       emisP, (const float4*)wIn2, Ivec, obs, out);
}